// Round 1
// 3087.374 us; speedup vs baseline: 1.5143x; 1.5143x over previous
//
#include <hip/hip_runtime.h>
#include <hip/hip_bf16.h>
#include <stdint.h>
#include <stddef.h>

// ---------------------------------------------------------------------------
// GRUEncoder: x[256,512,25,3] f32 -> 2-layer GRU(H=256) -> fc(hT) -> [256,256] f32
//
// Pipelined time-chunked schedule (chunk = TC steps):
//   cast_x  : x -> xb fp16 [T*B, 96] (t-major rows, K padded 75->96)
//   cast_w  : weights -> fp16; bias0/1 = b_ih + (r,z part of b_hh)
//   gemm0(0): xgA = xb[0] @ W_ih0^T + bias0
//   for c in 0..nc-1:
//     scan2 (32 WGs): layer-0 chunk c (xgA -> out0c, h0s)
//                  || layer-1 chunk c-1 (xgB -> h1s)     [concurrent CUs]
//     gemm1(c): xgB = out0c @ W_ih1^T + bias1
//     gemm0(c+1): xgA = xb[c+1] @ W_ih0^T + bias0
//   scan2 (L1-only drain) ; cast_h ; fc gemm
//
// The two scan halves are independent (disjoint batch-tile state, weights,
// CUs) -> layer scans overlap, halving scan wall-time. h carried in f32
// registers within a chunk and f32 globals across chunks -> identical
// numerics to a single 512-step scan. TC=32 keeps each gemm-written xg
// chunk (12.6 MB) L2/L3-resident for the immediately following scan.
// ---------------------------------------------------------------------------

typedef _Float16 f16;
typedef _Float16 f16x8 __attribute__((ext_vector_type(8)));
typedef float    f32x4 __attribute__((ext_vector_type(4)));

#define B_      256
#define T_      512
#define H_      256
#define G_      768      // 3*H
#define IN_RAW  75
#define KX      96       // padded input K
#define MROWS   (T_*B_)  // 131072

__device__ __forceinline__ float sigm(float x){ return 1.f/(1.f+__expf(-x)); }
__device__ __forceinline__ float tanh_(float x){ return 1.f - 2.f/(1.f+__expf(2.f*x)); }

// --------------------------------------------------------------------------
// cast_x: x[b][t][j] (f32) -> xb[t*256+b][96] (fp16, j>=75 zero)
// --------------------------------------------------------------------------
__global__ __launch_bounds__(256) void cast_x(const float* __restrict__ x,
                                              f16* __restrict__ xb){
  int idx = blockIdx.x*256 + threadIdx.x;        // grid*256 == 131072*96 exact
  int row = idx / KX;
  int j   = idx - row*KX;
  int t   = row >> 8;        // row = t*256 + b
  int b   = row & 255;
  float v = (j < IN_RAW) ? x[((size_t)b*T_ + t)*IN_RAW + j] : 0.f;
  xb[idx] = (f16)v;
}

// --------------------------------------------------------------------------
// cast_w: all weight casts + fused biases. grid*256 == 730624 exact.
// --------------------------------------------------------------------------
__global__ __launch_bounds__(256) void cast_w(
    const float* __restrict__ Wih0, const float* __restrict__ Whh0,
    const float* __restrict__ Wih1, const float* __restrict__ Whh1,
    const float* __restrict__ fcW,
    const float* __restrict__ bih0, const float* __restrict__ bhh0,
    const float* __restrict__ bih1, const float* __restrict__ bhh1,
    f16* __restrict__ W0h, f16* __restrict__ Whh0h, f16* __restrict__ Wih1h,
    f16* __restrict__ Whh1h, f16* __restrict__ fcWh,
    float* __restrict__ bias0, float* __restrict__ bias1){
  int i = blockIdx.x*256 + threadIdx.x;
  if (i < 73728){ int r = i/KX, j = i - r*KX;
    W0h[i] = (f16)((j < IN_RAW) ? Wih0[r*IN_RAW + j] : 0.f); return; }
  i -= 73728;
  if (i < 196608){ Whh0h[i] = (f16)Whh0[i]; return; } i -= 196608;
  if (i < 196608){ Wih1h[i] = (f16)Wih1[i]; return; } i -= 196608;
  if (i < 196608){ Whh1h[i] = (f16)Whh1[i]; return; } i -= 196608;
  if (i < 65536){ fcWh[i] = (f16)fcW[i]; return; } i -= 65536;
  if (i < 768){ bias0[i] = bih0[i] + (i < 512 ? bhh0[i] : 0.f); return; } i -= 768;
  if (i < 768){ bias1[i] = bih1[i] + (i < 512 ? bhh1[i] : 0.f); }
}

// --------------------------------------------------------------------------
// cast_h: h1s f32 [256*256] -> hT fp16
// --------------------------------------------------------------------------
__global__ __launch_bounds__(256) void cast_h(const float* __restrict__ hs,
                                              f16* __restrict__ hT){
  int i = blockIdx.x*256 + threadIdx.x;
  hT[i] = (f16)hs[i];
}

// --------------------------------------------------------------------------
// gemm_k: out[M,N] = A[M,K](fp16) @ W[N,K]^T(fp16) + bias.  No-LDS MFMA GEMM;
// W rows are L2-resident, A streamed. WG = 4 waves; wave owns WM=32 rows
// (2 A-frags) x BN cols -> 24 MFMA per 14 fragment loads.
// --------------------------------------------------------------------------
template<int K, int BN, bool OUTF32>
__global__ __launch_bounds__(256, 2) void gemm_k(const f16* __restrict__ A,
    const f16* __restrict__ W, const float* __restrict__ bias,
    void* __restrict__ outp, const int N){
  constexpr int NT = BN/16;
  const int tid  = threadIdx.x;
  const int wave = tid >> 6, lane = tid & 63;
  const int quad = lane >> 4, l16 = lane & 15;
  const long mbase = (long)blockIdx.x*128 + wave*32;
  const int  nbase = blockIdx.y*BN;
  f32x4 acc[2][NT] = {};
#pragma unroll 2
  for (int kc = 0; kc < K/32; ++kc){
    f16x8 a0 = *(const f16x8*)(A + (mbase +      l16)*K + kc*32 + quad*8);
    f16x8 a1 = *(const f16x8*)(A + (mbase + 16 + l16)*K + kc*32 + quad*8);
#pragma unroll
    for (int nt = 0; nt < NT; ++nt){
      f16x8 b = *(const f16x8*)(W + (long)(nbase + nt*16 + l16)*K + kc*32 + quad*8);
      acc[0][nt] = __builtin_amdgcn_mfma_f32_16x16x32_f16(a0, b, acc[0][nt], 0, 0, 0);
      acc[1][nt] = __builtin_amdgcn_mfma_f32_16x16x32_f16(a1, b, acc[1][nt], 0, 0, 0);
    }
  }
#pragma unroll
  for (int nt = 0; nt < NT; ++nt){
    const int col = nbase + nt*16 + l16;
    const float bv = bias[col];
#pragma unroll
    for (int af = 0; af < 2; ++af){
#pragma unroll
      for (int r = 0; r < 4; ++r){
        const long row = mbase + af*16 + quad*4 + r;   // D row = quad*4 + reg
        float v = acc[af][nt][r] + bv;
        if (OUTF32) ((float*)outp)[row*(long)N + col] = v;
        else        ((f16*)outp)[row*(long)N + col] = (f16)v;
      }
    }
  }
}

// --------------------------------------------------------------------------
// scan2: TC steps of BOTH GRU layers, pipelined with a 1-chunk skew.
// 32 WGs x 512 thr: WGs 0..15 run layer-0 (chunk c), WGs 16..31 run layer-1
// (chunk c-1). Halves are fully independent -> concurrent CUs.
// mask bit0 enables the layer-0 half, bit1 the layer-1 half.
// Body identical to the verified single-layer scan: W_hh register-resident
// (wave owns gate cols [w*32,+32) of r/z/n), h f32 in registers, hbuf fp16
// pitch 264, xg tile double-buffered in LDS with 1-step register prefetch.
// --------------------------------------------------------------------------
__global__ __launch_bounds__(512, 1) void scan2(
    const f16* __restrict__ xgL0, const f16* __restrict__ WhhL0,
    const float* __restrict__ bhhL0, float* __restrict__ hsL0,
    f16* __restrict__ out0,
    const f16* __restrict__ xgL1, const f16* __restrict__ WhhL1,
    const float* __restrict__ bhhL1, float* __restrict__ hsL1,
    const int TC, const int mask){
  __shared__ f16 hbuf[16*264];
  __shared__ f16 xgb[2][16*G_];
  const bool L1w = (blockIdx.x >= 16);
  if (L1w ? ((mask & 2) == 0) : ((mask & 1) == 0)) return;  // WG-uniform exit
  const f16*   xg     = L1w ? xgL1  : xgL0;
  const f16*   Whh    = L1w ? WhhL1 : WhhL0;
  const float* bhh    = L1w ? bhhL1 : bhhL0;
  float*       hstate = L1w ? hsL1  : hsL0;
  f16*         outp   = L1w ? (f16*)nullptr : out0;

  const int tid  = threadIdx.x;
  const int wave = tid >> 6, lane = tid & 63;
  const int quad = lane >> 4, l16 = lane & 15;
  const int b0   = (blockIdx.x & 15)*16;

  // register-resident weights: B-frag = W[ncol][k], 8 consecutive k per lane
  f16x8 w[2][3][8];
#pragma unroll
  for (int s = 0; s < 2; ++s)
#pragma unroll
    for (int g = 0; g < 3; ++g){
      const int ncol = g*256 + wave*32 + s*16 + l16;
#pragma unroll
      for (int kc = 0; kc < 8; ++kc)
        w[s][g][kc] = *(const f16x8*)(Whh + (size_t)ncol*H_ + kc*32 + quad*8);
    }
  // n-gate hidden bias (stays inside r*(...) term) -> accumulator init
  float bn[2] = { bhh[512 + wave*32 + l16], bhh[512 + wave*32 + 16 + l16] };

  // h state: lane owns (m=quad*4+r, j=wave*32+s*16+l16); covers 16x256 exactly
  float h[2][4];
#pragma unroll
  for (int s = 0; s < 2; ++s)
#pragma unroll
    for (int r = 0; r < 4; ++r){
      const int m = quad*4 + r, j = wave*32 + s*16 + l16;
      float hv = hstate[(size_t)(b0 + m)*H_ + j];
      h[s][r] = hv;
      hbuf[m*264 + j] = (f16)hv;
    }

  // stage xg(t=0)
  {
    const uint4* gs = (const uint4*)(xg + (size_t)b0*G_);
    uint4 r0 = gs[tid*3+0], r1 = gs[tid*3+1], r2 = gs[tid*3+2];
    uint4* ld = (uint4*)&xgb[0][0];
    ld[tid*3+0] = r0; ld[tid*3+1] = r1; ld[tid*3+2] = r2;
  }
  __syncthreads();

  for (int t = 0; t < TC; ++t){
    const int pb = t & 1;
    const bool pre = (t+1 < TC);
    uint4 p0, p1, p2;
    if (pre){  // prefetch next step's xg tile (latency hidden across the step)
      const uint4* gs = (const uint4*)(xg + (size_t)(t+1)*(B_*G_) + (size_t)b0*G_);
      p0 = gs[tid*3+0]; p1 = gs[tid*3+1]; p2 = gs[tid*3+2];
    }
#pragma unroll
    for (int s = 0; s < 2; ++s){
      f32x4 aR = {0,0,0,0}, aZ = {0,0,0,0};
      f32x4 aN = {bn[s], bn[s], bn[s], bn[s]};
#pragma unroll
      for (int kc = 0; kc < 8; ++kc){
        f16x8 a = *(const f16x8*)(&hbuf[l16*264 + kc*32 + quad*8]);
        aR = __builtin_amdgcn_mfma_f32_16x16x32_f16(a, w[s][0][kc], aR, 0,0,0);
        aZ = __builtin_amdgcn_mfma_f32_16x16x32_f16(a, w[s][1][kc], aZ, 0,0,0);
        aN = __builtin_amdgcn_mfma_f32_16x16x32_f16(a, w[s][2][kc], aN, 0,0,0);
      }
      const int j = wave*32 + s*16 + l16;
#pragma unroll
      for (int r = 0; r < 4; ++r){
        const int m = quad*4 + r;
        float xr = (float)xgb[pb][m*G_ + j];
        float xz = (float)xgb[pb][m*G_ + 256 + j];
        float xn = (float)xgb[pb][m*G_ + 512 + j];
        float rg = sigm(xr + aR[r]);
        float zg = sigm(xz + aZ[r]);
        float ng = tanh_(xn + rg*aN[r]);
        h[s][r] = (1.f - zg)*ng + zg*h[s][r];
      }
    }
    __syncthreads();   // all reads of hbuf h(t-1) / xgb[pb] complete
#pragma unroll
    for (int s = 0; s < 2; ++s){
      const int j = wave*32 + s*16 + l16;
#pragma unroll
      for (int r = 0; r < 4; ++r)
        hbuf[(quad*4 + r)*264 + j] = (f16)h[s][r];
    }
    if (pre){
      uint4* ld = (uint4*)&xgb[pb^1][0];
      ld[tid*3+0] = p0; ld[tid*3+1] = p1; ld[tid*3+2] = p2;
    }
    __syncthreads();   // h(t) in hbuf, xg(t+1) staged
    if (outp){         // coalesced h(t) store via hbuf round-trip
      const int rl = tid >> 5, col = (tid & 31)*8;
      f16x8 v = *(const f16x8*)&hbuf[rl*264 + col];
      *(f16x8*)(outp + ((size_t)t*B_ + b0 + rl)*H_ + col) = v;
    }
  }

#pragma unroll
  for (int s = 0; s < 2; ++s)
#pragma unroll
    for (int r = 0; r < 4; ++r)
      hstate[(size_t)(b0 + quad*4 + r)*H_ + wave*32 + s*16 + l16] = h[s][r];
}

// --------------------------------------------------------------------------
extern "C" void kernel_launch(void* const* d_in, const int* in_sizes, int n_in,
                              void* d_out, int out_size, void* d_ws, size_t ws_size,
                              hipStream_t stream){
  (void)in_sizes; (void)n_in; (void)out_size;
  const float* x    = (const float*)d_in[0];
  const float* Wih0 = (const float*)d_in[1];
  const float* Whh0 = (const float*)d_in[2];
  const float* bih0 = (const float*)d_in[3];
  const float* bhh0 = (const float*)d_in[4];
  const float* Wih1 = (const float*)d_in[5];
  const float* Whh1 = (const float*)d_in[6];
  const float* bih1 = (const float*)d_in[7];
  const float* bhh1 = (const float*)d_in[8];
  const float* fcW  = (const float*)d_in[9];
  const float* fcb  = (const float*)d_in[10];

  char* ws = (char*)d_ws;
  size_t off = 0;
  auto alloc = [&](size_t bytes) -> void* {
    void* p = ws + off; off += (bytes + 255) & ~(size_t)255; return p;
  };
  f16*   xb    = (f16*)  alloc((size_t)MROWS*KX*2);   // 25.2 MB
  f16*   W0h   = (f16*)  alloc((size_t)G_*KX*2);
  f16*   Whh0h = (f16*)  alloc((size_t)G_*H_*2);
  f16*   Wih1h = (f16*)  alloc((size_t)G_*H_*2);
  f16*   Whh1h = (f16*)  alloc((size_t)G_*H_*2);
  f16*   fcWh  = (f16*)  alloc((size_t)H_*H_*2);
  float* bias0 = (float*)alloc(G_*4);
  float* bias1 = (float*)alloc(G_*4);
  float* h0s   = (float*)alloc((size_t)B_*H_*4);      // h-state, both layers
  float* h1s   = (float*)alloc((size_t)B_*H_*4);      //   (adjacent: one memset)
  f16*   hTh   = (f16*)  alloc((size_t)B_*H_*2);
  const size_t fixed = off;

  // chunk size: TC=32 keeps each 12.6 MB xg chunk cache-resident between the
  // gemm that writes it and the scan that reads it; shrink if ws is tight.
  int TC = 32;
  while (TC > 8 && fixed + (size_t)TC*(2*393216 + 131072) + 1024 > ws_size) TC >>= 1;
  f16* xgA   = (f16*)alloc((size_t)TC*B_*G_*2);       // layer-0 input gates
  f16* xgB   = (f16*)alloc((size_t)TC*B_*G_*2);       // layer-1 input gates
  f16* out0c = (f16*)alloc((size_t)TC*B_*H_*2);
  const int nc = T_ / TC;

  hipMemsetAsync(h0s, 0, (size_t)B_*H_*4*2, stream);  // zero h0s+h1s (adjacent)
  hipLaunchKernelGGL(cast_x, dim3(49152), dim3(256), 0, stream, x, xb);
  hipLaunchKernelGGL(cast_w, dim3(2854), dim3(256), 0, stream,
                     Wih0, Whh0, Wih1, Whh1, fcW, bih0, bhh0, bih1, bhh1,
                     W0h, Whh0h, Wih1h, Whh1h, fcWh, bias0, bias1);

  // pipeline prologue: xgA = xb[chunk 0] @ W_ih0^T + bias0
  hipLaunchKernelGGL((gemm_k<96,192,false>), dim3(TC*2,4), dim3(256), 0, stream,
                     xb, W0h, bias0, (void*)xgA, G_);

  for (int c = 0; c < nc; ++c){
    const int mask = 1 | (c > 0 ? 2 : 0);
    // layer-0 chunk c  ||  layer-1 chunk c-1 (concurrent, disjoint CUs)
    hipLaunchKernelGGL(scan2, dim3(32), dim3(512), 0, stream,
                       xgA, Whh0h, bhh0, h0s, out0c,
                       xgB, Whh1h, bhh1, h1s, TC, mask);
    // xgB = out0c @ W_ih1^T + bias1   (consumed by layer-1 half next launch)
    hipLaunchKernelGGL((gemm_k<256,192,false>), dim3(TC*2,4), dim3(256), 0, stream,
                       out0c, Wih1h, bias1, (void*)xgB, G_);
    // xgA = xb[chunk c+1] @ W_ih0^T + bias0
    if (c+1 < nc)
      hipLaunchKernelGGL((gemm_k<96,192,false>), dim3(TC*2,4), dim3(256), 0, stream,
                         xb + (size_t)(c+1)*TC*B_*KX, W0h, bias0, (void*)xgA, G_);
  }
  // drain: layer-1 on final chunk
  hipLaunchKernelGGL(scan2, dim3(32), dim3(512), 0, stream,
                     xgA, Whh0h, bhh0, h0s, out0c,
                     xgB, Whh1h, bhh1, h1s, TC, 2);

  // embedding = hT @ fc_W^T + fc_b (f32 out)
  hipLaunchKernelGGL(cast_h, dim3(256), dim3(256), 0, stream, h1s, hTh);
  hipLaunchKernelGGL((gemm_k<256,64,true>), dim3(2,4), dim3(256), 0, stream,
                     hTh, fcWh, fcb, d_out, H_);
}

// Round 2
// 2971.098 us; speedup vs baseline: 1.5735x; 1.0391x over previous
//
#include <hip/hip_runtime.h>
#include <hip/hip_bf16.h>
#include <stdint.h>
#include <stddef.h>

// ---------------------------------------------------------------------------
// GRUEncoder: x[256,512,25,3] f32 -> 2-layer GRU(H=256) -> fc(hT) -> [256,256] f32
//
// Fused pipelined schedule (chunk = TC steps, 2-chunk layer skew):
//   cast_x ; cast_w ; gemm0(chunk0)
//   for i in 0..nc+1:   ONE launch: [scan L0 chunk i] || [scan L1 chunk i-2]
//                                   || [gemm0 chunk i+1] || [gemm1 chunk i-1]
//   cast_h ; fc gemm
//
// Scan uses swapped MFMA operands: D[gate rows x batch cols] = Whh * h.
//  - Whh fragments truly register-resident (192 VGPR, asm-pinned vs remat;
//    prior build remat'd them -> 384KB/WG/step L2 re-stream = the bottleneck)
//  - h fragment (B operand) shared by all 6 accumulators: 8 ds_read_b128/step
//  - xg gate values are per-lane exclusive -> loaded global->register with
//    1-step prefetch; no xg LDS staging at all
//  - single barrier/step via double-buffered hbuf (pitch 264)
// ---------------------------------------------------------------------------

typedef _Float16 f16;
typedef _Float16 f16x8 __attribute__((ext_vector_type(8)));
typedef _Float16 f16x4 __attribute__((ext_vector_type(4)));
typedef float    f32x4 __attribute__((ext_vector_type(4)));

#define B_      256
#define T_      512
#define H_      256
#define G_      768      // 3*H
#define IN_RAW  75
#define KX      96       // padded input K
#define MROWS   (T_*B_)  // 131072

__device__ __forceinline__ float sigm(float x){ return 1.f/(1.f+__expf(-x)); }
__device__ __forceinline__ float tanh_(float x){ return 1.f - 2.f/(1.f+__expf(2.f*x)); }

// --------------------------------------------------------------------------
// cast_x: x[b][t][j] (f32) -> xb[t*256+b][96] (fp16, j>=75 zero)
// --------------------------------------------------------------------------
__global__ __launch_bounds__(256) void cast_x(const float* __restrict__ x,
                                              f16* __restrict__ xb){
  int idx = blockIdx.x*256 + threadIdx.x;        // grid*256 == 131072*96 exact
  int row = idx / KX;
  int j   = idx - row*KX;
  int t   = row >> 8;        // row = t*256 + b
  int b   = row & 255;
  float v = (j < IN_RAW) ? x[((size_t)b*T_ + t)*IN_RAW + j] : 0.f;
  xb[idx] = (f16)v;
}

// --------------------------------------------------------------------------
// cast_w: all weight casts + fused biases. grid*256 == 730624 exact.
// --------------------------------------------------------------------------
__global__ __launch_bounds__(256) void cast_w(
    const float* __restrict__ Wih0, const float* __restrict__ Whh0,
    const float* __restrict__ Wih1, const float* __restrict__ Whh1,
    const float* __restrict__ fcW,
    const float* __restrict__ bih0, const float* __restrict__ bhh0,
    const float* __restrict__ bih1, const float* __restrict__ bhh1,
    f16* __restrict__ W0h, f16* __restrict__ Whh0h, f16* __restrict__ Wih1h,
    f16* __restrict__ Whh1h, f16* __restrict__ fcWh,
    float* __restrict__ bias0, float* __restrict__ bias1){
  int i = blockIdx.x*256 + threadIdx.x;
  if (i < 73728){ int r = i/KX, j = i - r*KX;
    W0h[i] = (f16)((j < IN_RAW) ? Wih0[r*IN_RAW + j] : 0.f); return; }
  i -= 73728;
  if (i < 196608){ Whh0h[i] = (f16)Whh0[i]; return; } i -= 196608;
  if (i < 196608){ Wih1h[i] = (f16)Wih1[i]; return; } i -= 196608;
  if (i < 196608){ Whh1h[i] = (f16)Whh1[i]; return; } i -= 196608;
  if (i < 65536){ fcWh[i] = (f16)fcW[i]; return; } i -= 65536;
  if (i < 768){ bias0[i] = bih0[i] + (i < 512 ? bhh0[i] : 0.f); return; } i -= 768;
  if (i < 768){ bias1[i] = bih1[i] + (i < 512 ? bhh1[i] : 0.f); }
}

// --------------------------------------------------------------------------
// cast_h: h1s f32 [256*256] -> hT fp16
// --------------------------------------------------------------------------
__global__ __launch_bounds__(256) void cast_h(const float* __restrict__ hs,
                                              f16* __restrict__ hT){
  int i = blockIdx.x*256 + threadIdx.x;
  hT[i] = (f16)hs[i];
}

// --------------------------------------------------------------------------
// gemm_k: out[M,N] = A[M,K](fp16) @ W[N,K]^T(fp16) + bias. 256-thread version
// kept for the prologue gemm and the fc epilogue.
// --------------------------------------------------------------------------
template<int K, int BN, bool OUTF32>
__global__ __launch_bounds__(256, 2) void gemm_k(const f16* __restrict__ A,
    const f16* __restrict__ W, const float* __restrict__ bias,
    void* __restrict__ outp, const int N){
  constexpr int NT = BN/16;
  const int tid  = threadIdx.x;
  const int wave = tid >> 6, lane = tid & 63;
  const int quad = lane >> 4, l16 = lane & 15;
  const long mbase = (long)blockIdx.x*128 + wave*32;
  const int  nbase = blockIdx.y*BN;
  f32x4 acc[2][NT] = {};
#pragma unroll 2
  for (int kc = 0; kc < K/32; ++kc){
    f16x8 a0 = *(const f16x8*)(A + (mbase +      l16)*K + kc*32 + quad*8);
    f16x8 a1 = *(const f16x8*)(A + (mbase + 16 + l16)*K + kc*32 + quad*8);
#pragma unroll
    for (int nt = 0; nt < NT; ++nt){
      f16x8 b = *(const f16x8*)(W + (long)(nbase + nt*16 + l16)*K + kc*32 + quad*8);
      acc[0][nt] = __builtin_amdgcn_mfma_f32_16x16x32_f16(a0, b, acc[0][nt], 0, 0, 0);
      acc[1][nt] = __builtin_amdgcn_mfma_f32_16x16x32_f16(a1, b, acc[1][nt], 0, 0, 0);
    }
  }
#pragma unroll
  for (int nt = 0; nt < NT; ++nt){
    const int col = nbase + nt*16 + l16;
    const float bv = bias[col];
#pragma unroll
    for (int af = 0; af < 2; ++af){
#pragma unroll
      for (int r = 0; r < 4; ++r){
        const long row = mbase + af*16 + quad*4 + r;   // D row = quad*4 + reg
        float v = acc[af][nt][r] + bv;
        if (OUTF32) ((float*)outp)[row*(long)N + col] = v;
        else        ((f16*)outp)[row*(long)N + col] = (f16)v;
      }
    }
  }
}

// --------------------------------------------------------------------------
// gemm_body: 512-thread (8-wave) GEMM tile for the fused kernel.
// Block covers 512 rows (2 sequential 256-row tiles) x 192 cols, N=768.
// --------------------------------------------------------------------------
template<int K>
__device__ __forceinline__ void gemm_body(const f16* __restrict__ A,
    const f16* __restrict__ W, const float* __restrict__ bias,
    f16* __restrict__ out, const int bx, const int by){
  const int tid  = threadIdx.x;
  const int wave = tid >> 6, lane = tid & 63;
  const int quad = lane >> 4, l16 = lane & 15;
  const int nbase = by*192;
#pragma unroll
  for (int mt = 0; mt < 2; ++mt){
    const long mbase = (long)bx*512 + mt*256 + wave*32;
    f32x4 acc[2][12] = {};
#pragma unroll 2
    for (int kc = 0; kc < K/32; ++kc){
      f16x8 a0 = *(const f16x8*)(A + (mbase +      l16)*K + kc*32 + quad*8);
      f16x8 a1 = *(const f16x8*)(A + (mbase + 16 + l16)*K + kc*32 + quad*8);
#pragma unroll
      for (int nt = 0; nt < 12; ++nt){
        f16x8 b = *(const f16x8*)(W + (long)(nbase + nt*16 + l16)*K + kc*32 + quad*8);
        acc[0][nt] = __builtin_amdgcn_mfma_f32_16x16x32_f16(a0, b, acc[0][nt], 0, 0, 0);
        acc[1][nt] = __builtin_amdgcn_mfma_f32_16x16x32_f16(a1, b, acc[1][nt], 0, 0, 0);
      }
    }
#pragma unroll
    for (int nt = 0; nt < 12; ++nt){
      const int col = nbase + nt*16 + l16;
      const float bv = bias[col];
#pragma unroll
      for (int af = 0; af < 2; ++af)
#pragma unroll
        for (int r = 0; r < 4; ++r)
          out[(mbase + af*16 + quad*4 + r)*(long)G_ + col] = (f16)(acc[af][nt][r] + bv);
    }
  }
}

// --------------------------------------------------------------------------
// scan_body: TC steps of one GRU layer, swapped-operand form.
// 16 WGs x 512 thr (8 waves); WG owns batch rows [bx*16,+16).
// D[gate rows x batch cols] = Whh(A, register-pinned) * h(B, from hbuf).
// Wave owns gate rows [w*32,+32) of r/z/n (6 accs). Gate inputs xg are
// per-lane exclusive -> global->register with 1-step prefetch (no LDS).
// Single barrier/step via double-buffered hbuf (pitch 264).
// --------------------------------------------------------------------------
__device__ __forceinline__ void scan_body(const f16* __restrict__ xg,
    const f16* __restrict__ Whh, const float* __restrict__ bhh,
    float* __restrict__ hstate, f16* __restrict__ out0,
    const int TC, const int bx){
  __shared__ f16 hbuf[2][16*264];
  const int tid  = threadIdx.x;
  const int wave = tid >> 6, lane = tid & 63;
  const int quad = lane >> 4, l16 = lane & 15;
  const int b0   = bx*16;
  const int jj   = wave*32 + quad*4;   // gate/hidden col base; s adds 16

  // A-frags: Whh[gate_row][k]; 8 consecutive k per lane (same layout as B was)
  f16x8 w[2][3][8];
#pragma unroll
  for (int s = 0; s < 2; ++s)
#pragma unroll
    for (int g = 0; g < 3; ++g)
#pragma unroll
      for (int kc = 0; kc < 8; ++kc)
        w[s][g][kc] = *(const f16x8*)(Whh + (size_t)(g*256 + wave*32 + s*16 + l16)*H_ + kc*32 + quad*8);
  // pin fragments in registers: opaque asm def prevents remat-from-load
#pragma unroll
  for (int s = 0; s < 2; ++s)
#pragma unroll
    for (int g = 0; g < 3; ++g)
#pragma unroll
      for (int kc = 0; kc < 8; ++kc)
        asm volatile("" : "+v"(w[s][g][kc]));

  // n-gate hidden bias, now indexed by D rows (quad*4+r)
  f32x4 bn[2];
#pragma unroll
  for (int s = 0; s < 2; ++s)
    bn[s] = *(const f32x4*)(bhh + 512 + jj + s*16);

  // h state: lane owns (batch=l16, j=jj+s*16+r)
  f32x4 h[2];
#pragma unroll
  for (int s = 0; s < 2; ++s){
    h[s] = *(const f32x4*)(hstate + (size_t)(b0 + l16)*H_ + jj + s*16);
    f16x4 hh;
#pragma unroll
    for (int r = 0; r < 4; ++r) hh[r] = (f16)h[s][r];
    *(f16x4*)&hbuf[0][l16*264 + jj + s*16] = hh;
  }

  // per-lane xg base: row = b0+l16, cols jj + {g*256, s*16}
  const f16* xgl = xg + (size_t)(b0 + l16)*G_ + jj;
  f16x4 cur[6], nxt[6];
#pragma unroll
  for (int s = 0; s < 2; ++s)
#pragma unroll
    for (int g = 0; g < 3; ++g)
      cur[s*3+g] = *(const f16x4*)(xgl + g*256 + s*16);

  __syncthreads();

  for (int t = 0; t < TC; ++t){
    const int  pb  = t & 1;
    const bool pre = (t+1 < TC);
    if (pre){  // prefetch next step's gate inputs (latency hidden across step)
      const f16* xn_ = xgl + (size_t)(t+1)*(B_*G_);
#pragma unroll
      for (int s = 0; s < 2; ++s)
#pragma unroll
        for (int g = 0; g < 3; ++g)
          nxt[s*3+g] = *(const f16x4*)(xn_ + g*256 + s*16);
    }
    f32x4 acc[2][3];
#pragma unroll
    for (int s = 0; s < 2; ++s){
      acc[s][0] = (f32x4){0.f,0.f,0.f,0.f};
      acc[s][1] = (f32x4){0.f,0.f,0.f,0.f};
      acc[s][2] = bn[s];
    }
#pragma unroll
    for (int kc = 0; kc < 8; ++kc){
      f16x8 hf = *(const f16x8*)(&hbuf[pb][l16*264 + kc*32 + quad*8]);
#pragma unroll
      for (int s = 0; s < 2; ++s){
        acc[s][0] = __builtin_amdgcn_mfma_f32_16x16x32_f16(w[s][0][kc], hf, acc[s][0], 0,0,0);
        acc[s][1] = __builtin_amdgcn_mfma_f32_16x16x32_f16(w[s][1][kc], hf, acc[s][1], 0,0,0);
        acc[s][2] = __builtin_amdgcn_mfma_f32_16x16x32_f16(w[s][2][kc], hf, acc[s][2], 0,0,0);
      }
    }
#pragma unroll
    for (int s = 0; s < 2; ++s){
      f16x4 hh;
#pragma unroll
      for (int r = 0; r < 4; ++r){
        float rg = sigm((float)cur[s*3+0][r] + acc[s][0][r]);
        float zg = sigm((float)cur[s*3+1][r] + acc[s][1][r]);
        float ng = tanh_((float)cur[s*3+2][r] + rg*acc[s][2][r]);
        float hv = (1.f - zg)*ng + zg*h[s][r];
        h[s][r] = hv;
        hh[r]   = (f16)hv;
      }
      *(f16x4*)&hbuf[pb^1][l16*264 + jj + s*16] = hh;   // h(t) for next step
      if (out0)
        *(f16x4*)(out0 + ((size_t)t*B_ + b0 + l16)*H_ + jj + s*16) = hh;
    }
    if (pre){
#pragma unroll
      for (int k = 0; k < 6; ++k) cur[k] = nxt[k];
    }
    __syncthreads();   // h(t) visible in hbuf[pb^1] for step t+1
  }

#pragma unroll
  for (int s = 0; s < 2; ++s)
    *(f32x4*)(hstate + (size_t)(b0 + l16)*H_ + jj + s*16) = h[s];
}

// --------------------------------------------------------------------------
// fused: [scan L0] || [scan L1] || [gemm0 next chunk] || [gemm1 prev chunk]
// blocks: [0,16) L0, [16,32) L1, [32,32+2TC) gemm0, [32+2TC,32+4TC) gemm1.
// mask: bit0 L0, bit1 L1, bit2 gemm0, bit3 gemm1.
// --------------------------------------------------------------------------
__global__ __launch_bounds__(512, 2) void fused(
    const f16* __restrict__ xg0, const f16* __restrict__ Whh0,
    const float* __restrict__ bhh0, float* __restrict__ h0s,
    f16* __restrict__ out0w,
    const f16* __restrict__ xg1, const f16* __restrict__ Whh1,
    const float* __restrict__ bhh1, float* __restrict__ h1s,
    const f16* __restrict__ g0A, const f16* __restrict__ g0W,
    const float* __restrict__ g0b, f16* __restrict__ g0out,
    const f16* __restrict__ g1A, const f16* __restrict__ g1W,
    const float* __restrict__ g1b, f16* __restrict__ g1out,
    const int TC, const int mask){
  const int bid = blockIdx.x;
  if (bid < 16){
    if (!(mask & 1)) return;
    scan_body(xg0, Whh0, bhh0, h0s, out0w, TC, bid);
  } else if (bid < 32){
    if (!(mask & 2)) return;
    scan_body(xg1, Whh1, bhh1, h1s, (f16*)nullptr, TC, bid - 16);
  } else {
    int g = bid - 32;
    const int half = TC/2;               // row-blocks of 512 per gemm
    if (g < 2*TC){
      if (!(mask & 4)) return;
      gemm_body<96>(g0A, g0W, g0b, g0out, g % half, g / half);
    } else {
      g -= 2*TC;
      if (!(mask & 8)) return;
      gemm_body<256>(g1A, g1W, g1b, g1out, g % half, g / half);
    }
  }
}

// --------------------------------------------------------------------------
extern "C" void kernel_launch(void* const* d_in, const int* in_sizes, int n_in,
                              void* d_out, int out_size, void* d_ws, size_t ws_size,
                              hipStream_t stream){
  (void)in_sizes; (void)n_in; (void)out_size;
  const float* x    = (const float*)d_in[0];
  const float* Wih0 = (const float*)d_in[1];
  const float* Whh0 = (const float*)d_in[2];
  const float* bih0 = (const float*)d_in[3];
  const float* bhh0 = (const float*)d_in[4];
  const float* Wih1 = (const float*)d_in[5];
  const float* Whh1 = (const float*)d_in[6];
  const float* bih1 = (const float*)d_in[7];
  const float* bhh1 = (const float*)d_in[8];
  const float* fcW  = (const float*)d_in[9];
  const float* fcb  = (const float*)d_in[10];

  char* ws = (char*)d_ws;
  size_t off = 0;
  auto alloc = [&](size_t bytes) -> void* {
    void* p = ws + off; off += (bytes + 255) & ~(size_t)255; return p;
  };
  f16*   xb    = (f16*)  alloc((size_t)MROWS*KX*2);   // 25.2 MB
  f16*   W0h   = (f16*)  alloc((size_t)G_*KX*2);
  f16*   Whh0h = (f16*)  alloc((size_t)G_*H_*2);
  f16*   Wih1h = (f16*)  alloc((size_t)G_*H_*2);
  f16*   Whh1h = (f16*)  alloc((size_t)G_*H_*2);
  f16*   fcWh  = (f16*)  alloc((size_t)H_*H_*2);
  float* bias0 = (float*)alloc(G_*4);
  float* bias1 = (float*)alloc(G_*4);
  float* h0s   = (float*)alloc((size_t)B_*H_*4);      // h-state, both layers
  float* h1s   = (float*)alloc((size_t)B_*H_*4);      //   (adjacent: one memset)
  f16*   hTh   = (f16*)  alloc((size_t)B_*H_*2);
  const size_t fixed = off;

  // TC=32: double-buffered xg (both layers) + out0. Per-TC bytes:
  // 4*B*G*2 + 2*B*H*2 = 1,835,008. Fallback shrink if ws is tight.
  int TC = 32;
  while (TC > 8 && fixed + (size_t)TC*1835008 + 1024 > ws_size) TC >>= 1;
  f16* xg0[2], *xg1[2], *out0[2];
  xg0[0]  = (f16*)alloc((size_t)TC*B_*G_*2);
  xg0[1]  = (f16*)alloc((size_t)TC*B_*G_*2);
  xg1[0]  = (f16*)alloc((size_t)TC*B_*G_*2);
  xg1[1]  = (f16*)alloc((size_t)TC*B_*G_*2);
  out0[0] = (f16*)alloc((size_t)TC*B_*H_*2);
  out0[1] = (f16*)alloc((size_t)TC*B_*H_*2);
  const int nc = T_ / TC;

  hipMemsetAsync(h0s, 0, (size_t)B_*H_*4*2, stream);  // zero h0s+h1s (adjacent)
  hipLaunchKernelGGL(cast_x, dim3(49152), dim3(256), 0, stream, x, xb);
  hipLaunchKernelGGL(cast_w, dim3(2854), dim3(256), 0, stream,
                     Wih0, Whh0, Wih1, Whh1, fcW, bih0, bhh0, bih1, bhh1,
                     W0h, Whh0h, Wih1h, Whh1h, fcWh, bias0, bias1);

  // prologue: xg0[0] = xb[chunk 0] @ W_ih0^T + bias0
  hipLaunchKernelGGL((gemm_k<96,192,false>), dim3(TC*2,4), dim3(256), 0, stream,
                     xb, W0h, bias0, (void*)xg0[0], G_);

  const dim3 grid(32 + 4*TC);
  for (int i = 0; i <= nc + 1; ++i){
    int mask = 0;
    if (i < nc)            mask |= 1;   // L0 scans chunk i
    if (i >= 2)            mask |= 2;   // L1 scans chunk i-2
    if (i + 1 < nc)        mask |= 4;   // gemm0 builds chunk i+1
    if (i >= 1 && i <= nc) mask |= 8;   // gemm1 builds chunk i-1
    hipLaunchKernelGGL(fused, grid, dim3(512), 0, stream,
                       xg0[i&1], Whh0h, bhh0, h0s, out0[i&1],
                       xg1[i&1], Whh1h, bhh1, h1s,
                       xb + (size_t)(i+1)*TC*B_*KX, W0h, bias0, xg0[(i+1)&1],
                       out0[(i+1)&1], Wih1h, bias1, xg1[(i+1)&1],
                       TC, mask);
  }

  // embedding = hT @ fc_W^T + fc_b (f32 out)
  hipLaunchKernelGGL(cast_h, dim3(256), dim3(256), 0, stream, h1s, hTh);
  hipLaunchKernelGGL((gemm_k<256,64,true>), dim3(2,4), dim3(256), 0, stream,
                     hTh, fcWh, fcb, d_out, H_);
}

// Round 3
// 1955.746 us; speedup vs baseline: 2.3904x; 1.5192x over previous
//
#include <hip/hip_runtime.h>
#include <hip/hip_bf16.h>
#include <stdint.h>
#include <stddef.h>

// ---------------------------------------------------------------------------
// GRUEncoder: x[256,512,25,3] f32 -> 2-layer GRU(H=256) -> fc(hT) -> [256,256] f32
//
// Fused pipelined schedule (chunk = TC steps, 2-chunk layer skew):
//   cast_x ; cast_w ; gemm0(chunk0)
//   for i in 0..nc+1:   ONE launch: [scan L0 chunk i] || [scan L1 chunk i-2]
//                                   || [gemm0 chunk i+1] || [gemm1 chunk i-1]
//   cast_h ; fc gemm
//
// Scan, swapped MFMA operands: D[gate rows x batch cols] = Whh * h.
// Register budget is THE constraint: 512-thr WG => hard cap 256 VGPR/lane.
// Whole Whh = 192 VGPR/lane (irreducible at 512 lanes) + ~80 working set
// spilled catastrophically in the previous build (VGPR_Count=128 => scratch
// reload every step was the bottleneck). This build fits by construction:
//   - r,z gates + n-gate kc<4 register-resident: 40 frags = 160 VGPR
//   - n-gate kc>=4 streamed from LDS (64KB, A-frag-ordered, conflict-free)
//   - no separate prefetch regs (t+1 gates loaded into cur after last use)
//   - n-bias read from LDS per step
//  => peak ~240 VGPR < 256 cap, no spill.
// ---------------------------------------------------------------------------

typedef _Float16 f16;
typedef _Float16 f16x8 __attribute__((ext_vector_type(8)));
typedef _Float16 f16x4 __attribute__((ext_vector_type(4)));
typedef float    f32x4 __attribute__((ext_vector_type(4)));

#define B_      256
#define T_      512
#define H_      256
#define G_      768      // 3*H
#define IN_RAW  75
#define KX      96       // padded input K
#define MROWS   (T_*B_)  // 131072

__device__ __forceinline__ float sigm(float x){ return 1.f/(1.f+__expf(-x)); }
__device__ __forceinline__ float tanh_(float x){ return 1.f - 2.f/(1.f+__expf(2.f*x)); }

// --------------------------------------------------------------------------
// cast_x: x[b][t][j] (f32) -> xb[t*256+b][96] (fp16, j>=75 zero)
// --------------------------------------------------------------------------
__global__ __launch_bounds__(256) void cast_x(const float* __restrict__ x,
                                              f16* __restrict__ xb){
  int idx = blockIdx.x*256 + threadIdx.x;        // grid*256 == 131072*96 exact
  int row = idx / KX;
  int j   = idx - row*KX;
  int t   = row >> 8;        // row = t*256 + b
  int b   = row & 255;
  float v = (j < IN_RAW) ? x[((size_t)b*T_ + t)*IN_RAW + j] : 0.f;
  xb[idx] = (f16)v;
}

// --------------------------------------------------------------------------
// cast_w: all weight casts + fused biases. grid*256 == 730624 exact.
// --------------------------------------------------------------------------
__global__ __launch_bounds__(256) void cast_w(
    const float* __restrict__ Wih0, const float* __restrict__ Whh0,
    const float* __restrict__ Wih1, const float* __restrict__ Whh1,
    const float* __restrict__ fcW,
    const float* __restrict__ bih0, const float* __restrict__ bhh0,
    const float* __restrict__ bih1, const float* __restrict__ bhh1,
    f16* __restrict__ W0h, f16* __restrict__ Whh0h, f16* __restrict__ Wih1h,
    f16* __restrict__ Whh1h, f16* __restrict__ fcWh,
    float* __restrict__ bias0, float* __restrict__ bias1){
  int i = blockIdx.x*256 + threadIdx.x;
  if (i < 73728){ int r = i/KX, j = i - r*KX;
    W0h[i] = (f16)((j < IN_RAW) ? Wih0[r*IN_RAW + j] : 0.f); return; }
  i -= 73728;
  if (i < 196608){ Whh0h[i] = (f16)Whh0[i]; return; } i -= 196608;
  if (i < 196608){ Wih1h[i] = (f16)Wih1[i]; return; } i -= 196608;
  if (i < 196608){ Whh1h[i] = (f16)Whh1[i]; return; } i -= 196608;
  if (i < 65536){ fcWh[i] = (f16)fcW[i]; return; } i -= 65536;
  if (i < 768){ bias0[i] = bih0[i] + (i < 512 ? bhh0[i] : 0.f); return; } i -= 768;
  if (i < 768){ bias1[i] = bih1[i] + (i < 512 ? bhh1[i] : 0.f); }
}

// --------------------------------------------------------------------------
// cast_h: h1s f32 [256*256] -> hT fp16
// --------------------------------------------------------------------------
__global__ __launch_bounds__(256) void cast_h(const float* __restrict__ hs,
                                              f16* __restrict__ hT){
  int i = blockIdx.x*256 + threadIdx.x;
  hT[i] = (f16)hs[i];
}

// --------------------------------------------------------------------------
// gemm_k: out[M,N] = A[M,K](fp16) @ W[N,K]^T(fp16) + bias. 256-thread version
// kept for the prologue gemm and the fc epilogue.
// --------------------------------------------------------------------------
template<int K, int BN, bool OUTF32>
__global__ __launch_bounds__(256, 2) void gemm_k(const f16* __restrict__ A,
    const f16* __restrict__ W, const float* __restrict__ bias,
    void* __restrict__ outp, const int N){
  constexpr int NT = BN/16;
  const int tid  = threadIdx.x;
  const int wave = tid >> 6, lane = tid & 63;
  const int quad = lane >> 4, l16 = lane & 15;
  const long mbase = (long)blockIdx.x*128 + wave*32;
  const int  nbase = blockIdx.y*BN;
  f32x4 acc[2][NT] = {};
#pragma unroll 2
  for (int kc = 0; kc < K/32; ++kc){
    f16x8 a0 = *(const f16x8*)(A + (mbase +      l16)*K + kc*32 + quad*8);
    f16x8 a1 = *(const f16x8*)(A + (mbase + 16 + l16)*K + kc*32 + quad*8);
#pragma unroll
    for (int nt = 0; nt < NT; ++nt){
      f16x8 b = *(const f16x8*)(W + (long)(nbase + nt*16 + l16)*K + kc*32 + quad*8);
      acc[0][nt] = __builtin_amdgcn_mfma_f32_16x16x32_f16(a0, b, acc[0][nt], 0, 0, 0);
      acc[1][nt] = __builtin_amdgcn_mfma_f32_16x16x32_f16(a1, b, acc[1][nt], 0, 0, 0);
    }
  }
#pragma unroll
  for (int nt = 0; nt < NT; ++nt){
    const int col = nbase + nt*16 + l16;
    const float bv = bias[col];
#pragma unroll
    for (int af = 0; af < 2; ++af){
#pragma unroll
      for (int r = 0; r < 4; ++r){
        const long row = mbase + af*16 + quad*4 + r;   // D row = quad*4 + reg
        float v = acc[af][nt][r] + bv;
        if (OUTF32) ((float*)outp)[row*(long)N + col] = v;
        else        ((f16*)outp)[row*(long)N + col] = (f16)v;
      }
    }
  }
}

// --------------------------------------------------------------------------
// gemm_body: 512-thread (8-wave) GEMM tile for the fused kernel.
// Block covers 512 rows (2 sequential 256-row tiles) x 192 cols, N=768.
// --------------------------------------------------------------------------
template<int K>
__device__ __forceinline__ void gemm_body(const f16* __restrict__ A,
    const f16* __restrict__ W, const float* __restrict__ bias,
    f16* __restrict__ out, const int bx, const int by){
  const int tid  = threadIdx.x;
  const int wave = tid >> 6, lane = tid & 63;
  const int quad = lane >> 4, l16 = lane & 15;
  const int nbase = by*192;
#pragma unroll
  for (int mt = 0; mt < 2; ++mt){
    const long mbase = (long)bx*512 + mt*256 + wave*32;
    f32x4 acc[2][12] = {};
#pragma unroll 2
    for (int kc = 0; kc < K/32; ++kc){
      f16x8 a0 = *(const f16x8*)(A + (mbase +      l16)*K + kc*32 + quad*8);
      f16x8 a1 = *(const f16x8*)(A + (mbase + 16 + l16)*K + kc*32 + quad*8);
#pragma unroll
      for (int nt = 0; nt < 12; ++nt){
        f16x8 b = *(const f16x8*)(W + (long)(nbase + nt*16 + l16)*K + kc*32 + quad*8);
        acc[0][nt] = __builtin_amdgcn_mfma_f32_16x16x32_f16(a0, b, acc[0][nt], 0, 0, 0);
        acc[1][nt] = __builtin_amdgcn_mfma_f32_16x16x32_f16(a1, b, acc[1][nt], 0, 0, 0);
      }
    }
#pragma unroll
    for (int nt = 0; nt < 12; ++nt){
      const int col = nbase + nt*16 + l16;
      const float bv = bias[col];
#pragma unroll
      for (int af = 0; af < 2; ++af)
#pragma unroll
        for (int r = 0; r < 4; ++r)
          out[(mbase + af*16 + quad*4 + r)*(long)G_ + col] = (f16)(acc[af][nt][r] + bv);
    }
  }
}

// --------------------------------------------------------------------------
// scan_body: TC steps of one GRU layer, swapped-operand form, register-FIT.
// 16 WGs x 512 thr (8 waves); WG owns batch rows [bx*16,+16).
// D[gate rows x batch cols] = Whh(A) * h(B, from hbuf).
// Wave owns gate rows [w*32,+32) of r/z/n.
//   r,z all kc + n kc<4:  40 frags = 160 VGPR, asm-pinned (fits now)
//   n kc>=4: streamed from nlds per step (conflict-free ds_read_b128)
// Gate inputs xg loaded global->cur after last use (no extra prefetch regs).
// Single barrier/step via double-buffered hbuf (pitch 264).
// --------------------------------------------------------------------------
__device__ __forceinline__ void scan_body(const f16* __restrict__ xg,
    const f16* __restrict__ Whh, const float* __restrict__ bhh,
    float* __restrict__ hstate, f16* __restrict__ out0,
    const int TC, const int bx){
  __shared__ f16   hbuf[2][16*264];
  __shared__ f16   nlds[32768];      // 64KB: n-gate frags kc 4..7, A-frag order
  __shared__ float bnlds[256];       // n-gate hidden bias
  const int tid  = threadIdx.x;
  const int wave = tid >> 6, lane = tid & 63;
  const int quad = lane >> 4, l16 = lane & 15;
  const int b0   = bx*16;
  const int jj   = wave*32 + quad*4;   // D-row base; s adds 16

  // resident A-frags: Whh[gate_row][k]; 8 consecutive k per lane
  f16x8 w[2][2][8];   // [s][g: r,z][kc]
  f16x8 wn[2][4];     // [s][kc<4] of n gate
#pragma unroll
  for (int s = 0; s < 2; ++s){
#pragma unroll
    for (int g = 0; g < 2; ++g)
#pragma unroll
      for (int kc = 0; kc < 8; ++kc)
        w[s][g][kc] = *(const f16x8*)(Whh + (size_t)(g*256 + wave*32 + s*16 + l16)*H_ + kc*32 + quad*8);
#pragma unroll
    for (int kc = 0; kc < 4; ++kc)
      wn[s][kc] = *(const f16x8*)(Whh + (size_t)(512 + wave*32 + s*16 + l16)*H_ + kc*32 + quad*8);
  }
  // pin resident fragments (demand fits the 256-reg cap -> no spill now)
#pragma unroll
  for (int s = 0; s < 2; ++s){
#pragma unroll
    for (int g = 0; g < 2; ++g)
#pragma unroll
      for (int kc = 0; kc < 8; ++kc)
        asm volatile("" : "+v"(w[s][g][kc]));
#pragma unroll
    for (int kc = 0; kc < 4; ++kc)
      asm volatile("" : "+v"(wn[s][kc]));
  }

  // stage nlds: piece p = frag f (=(wave*2+s)*4 + kc-4) * 64 + lane; 16B each
#pragma unroll
  for (int i = 0; i < 8; ++i){
    const int p  = tid*8 + i;
    const int f  = p >> 6, L = p & 63;
    const int wv = f >> 3, ss = (f >> 2) & 1, kcm = f & 3;
    const int row = 512 + wv*32 + ss*16 + (L & 15);
    const int k   = (kcm + 4)*32 + (L >> 4)*8;
    *(f16x8*)&nlds[p*8] = *(const f16x8*)(Whh + (size_t)row*H_ + k);
  }
  if (tid < 256) bnlds[tid] = bhh[512 + tid];

  // h state: lane owns (batch=l16, j=jj+s*16+r)
  f32x4 h[2];
#pragma unroll
  for (int s = 0; s < 2; ++s){
    h[s] = *(const f32x4*)(hstate + (size_t)(b0 + l16)*H_ + jj + s*16);
    f16x4 hh;
#pragma unroll
    for (int r = 0; r < 4; ++r) hh[r] = (f16)h[s][r];
    *(f16x4*)&hbuf[0][l16*264 + jj + s*16] = hh;
  }

  // per-lane xg base: row = b0+l16, cols jj + {g*256, s*16}
  const f16* xgl = xg + (size_t)(b0 + l16)*G_ + jj;
  f16x4 cur[6];
#pragma unroll
  for (int s = 0; s < 2; ++s)
#pragma unroll
    for (int g = 0; g < 3; ++g)
      cur[s*3+g] = *(const f16x4*)(xgl + g*256 + s*16);

  __syncthreads();   // hbuf[0], nlds, bnlds ready

  for (int t = 0; t < TC; ++t){
    const int pb = t & 1;
    f32x4 acc[2][3] = {};
#pragma unroll
    for (int kc = 0; kc < 8; ++kc){
      f16x8 hf = *(const f16x8*)(&hbuf[pb][l16*264 + kc*32 + quad*8]);
#pragma unroll
      for (int s = 0; s < 2; ++s){
        acc[s][0] = __builtin_amdgcn_mfma_f32_16x16x32_f16(w[s][0][kc], hf, acc[s][0], 0,0,0);
        acc[s][1] = __builtin_amdgcn_mfma_f32_16x16x32_f16(w[s][1][kc], hf, acc[s][1], 0,0,0);
        f16x8 wnf;
        if (kc < 4) wnf = wn[s][kc];
        else        wnf = *(const f16x8*)&nlds[(((wave*2+s)*4 + (kc-4))*64 + lane)*8];
        acc[s][2] = __builtin_amdgcn_mfma_f32_16x16x32_f16(wnf, hf, acc[s][2], 0,0,0);
      }
    }
    f16x4 hh[2];
#pragma unroll
    for (int s = 0; s < 2; ++s){
      const f32x4 bnv = *(const f32x4*)&bnlds[jj + s*16];
#pragma unroll
      for (int r = 0; r < 4; ++r){
        float rg = sigm((float)cur[s*3+0][r] + acc[s][0][r]);
        float zg = sigm((float)cur[s*3+1][r] + acc[s][1][r]);
        float ng = tanh_((float)cur[s*3+2][r] + rg*(acc[s][2][r] + bnv[r]));
        float hv = (1.f - zg)*ng + zg*h[s][r];
        h[s][r] = hv;
        hh[s][r] = (f16)hv;
      }
    }
    if (t+1 < TC){  // load t+1 gates into cur (old cur fully consumed above);
      const f16* xn_ = xgl + (size_t)(t+1)*(B_*G_);   // latency covered by
#pragma unroll                                        // barrier + next MFMA
      for (int s = 0; s < 2; ++s)
#pragma unroll
        for (int g = 0; g < 3; ++g)
          cur[s*3+g] = *(const f16x4*)(xn_ + g*256 + s*16);
    }
#pragma unroll
    for (int s = 0; s < 2; ++s){
      *(f16x4*)&hbuf[pb^1][l16*264 + jj + s*16] = hh[s];   // h(t) for t+1
      if (out0)
        *(f16x4*)(out0 + ((size_t)t*B_ + b0 + l16)*H_ + jj + s*16) = hh[s];
    }
    __syncthreads();   // h(t) visible in hbuf[pb^1] for step t+1
  }

#pragma unroll
  for (int s = 0; s < 2; ++s)
    *(f32x4*)(hstate + (size_t)(b0 + l16)*H_ + jj + s*16) = h[s];
}

// --------------------------------------------------------------------------
// fused: [scan L0] || [scan L1] || [gemm0 next chunk] || [gemm1 prev chunk]
// blocks: [0,16) L0, [16,32) L1, [32,32+2TC) gemm0, [32+2TC,32+4TC) gemm1.
// mask: bit0 L0, bit1 L1, bit2 gemm0, bit3 gemm1.
// --------------------------------------------------------------------------
__global__ __launch_bounds__(512, 2) void fused(
    const f16* __restrict__ xg0, const f16* __restrict__ Whh0,
    const float* __restrict__ bhh0, float* __restrict__ h0s,
    f16* __restrict__ out0w,
    const f16* __restrict__ xg1, const f16* __restrict__ Whh1,
    const float* __restrict__ bhh1, float* __restrict__ h1s,
    const f16* __restrict__ g0A, const f16* __restrict__ g0W,
    const float* __restrict__ g0b, f16* __restrict__ g0out,
    const f16* __restrict__ g1A, const f16* __restrict__ g1W,
    const float* __restrict__ g1b, f16* __restrict__ g1out,
    const int TC, const int mask){
  const int bid = blockIdx.x;
  if (bid < 16){
    if (!(mask & 1)) return;
    scan_body(xg0, Whh0, bhh0, h0s, out0w, TC, bid);
  } else if (bid < 32){
    if (!(mask & 2)) return;
    scan_body(xg1, Whh1, bhh1, h1s, (f16*)nullptr, TC, bid - 16);
  } else {
    int g = bid - 32;
    const int half = TC/2;               // row-blocks of 512 per gemm
    if (g < 2*TC){
      if (!(mask & 4)) return;
      gemm_body<96>(g0A, g0W, g0b, g0out, g % half, g / half);
    } else {
      g -= 2*TC;
      if (!(mask & 8)) return;
      gemm_body<256>(g1A, g1W, g1b, g1out, g % half, g / half);
    }
  }
}

// --------------------------------------------------------------------------
extern "C" void kernel_launch(void* const* d_in, const int* in_sizes, int n_in,
                              void* d_out, int out_size, void* d_ws, size_t ws_size,
                              hipStream_t stream){
  (void)in_sizes; (void)n_in; (void)out_size;
  const float* x    = (const float*)d_in[0];
  const float* Wih0 = (const float*)d_in[1];
  const float* Whh0 = (const float*)d_in[2];
  const float* bih0 = (const float*)d_in[3];
  const float* bhh0 = (const float*)d_in[4];
  const float* Wih1 = (const float*)d_in[5];
  const float* Whh1 = (const float*)d_in[6];
  const float* bih1 = (const float*)d_in[7];
  const float* bhh1 = (const float*)d_in[8];
  const float* fcW  = (const float*)d_in[9];
  const float* fcb  = (const float*)d_in[10];

  char* ws = (char*)d_ws;
  size_t off = 0;
  auto alloc = [&](size_t bytes) -> void* {
    void* p = ws + off; off += (bytes + 255) & ~(size_t)255; return p;
  };
  f16*   xb    = (f16*)  alloc((size_t)MROWS*KX*2);   // 25.2 MB
  f16*   W0h   = (f16*)  alloc((size_t)G_*KX*2);
  f16*   Whh0h = (f16*)  alloc((size_t)G_*H_*2);
  f16*   Wih1h = (f16*)  alloc((size_t)G_*H_*2);
  f16*   Whh1h = (f16*)  alloc((size_t)G_*H_*2);
  f16*   fcWh  = (f16*)  alloc((size_t)H_*H_*2);
  float* bias0 = (float*)alloc(G_*4);
  float* bias1 = (float*)alloc(G_*4);
  float* h0s   = (float*)alloc((size_t)B_*H_*4);      // h-state, both layers
  float* h1s   = (float*)alloc((size_t)B_*H_*4);      //   (adjacent: one memset)
  f16*   hTh   = (f16*)  alloc((size_t)B_*H_*2);
  const size_t fixed = off;

  // TC=32: double-buffered xg (both layers) + out0. Per-TC bytes:
  // 4*B*G*2 + 2*B*H*2 = 1,835,008. Fallback shrink if ws is tight.
  int TC = 32;
  while (TC > 8 && fixed + (size_t)TC*1835008 + 1024 > ws_size) TC >>= 1;
  f16* xg0[2], *xg1[2], *out0[2];
  xg0[0]  = (f16*)alloc((size_t)TC*B_*G_*2);
  xg0[1]  = (f16*)alloc((size_t)TC*B_*G_*2);
  xg1[0]  = (f16*)alloc((size_t)TC*B_*G_*2);
  xg1[1]  = (f16*)alloc((size_t)TC*B_*G_*2);
  out0[0] = (f16*)alloc((size_t)TC*B_*H_*2);
  out0[1] = (f16*)alloc((size_t)TC*B_*H_*2);
  const int nc = T_ / TC;

  hipMemsetAsync(h0s, 0, (size_t)B_*H_*4*2, stream);  // zero h0s+h1s (adjacent)
  hipLaunchKernelGGL(cast_x, dim3(49152), dim3(256), 0, stream, x, xb);
  hipLaunchKernelGGL(cast_w, dim3(2854), dim3(256), 0, stream,
                     Wih0, Whh0, Wih1, Whh1, fcW, bih0, bhh0, bih1, bhh1,
                     W0h, Whh0h, Wih1h, Whh1h, fcWh, bias0, bias1);

  // prologue: xg0[0] = xb[chunk 0] @ W_ih0^T + bias0
  hipLaunchKernelGGL((gemm_k<96,192,false>), dim3(TC*2,4), dim3(256), 0, stream,
                     xb, W0h, bias0, (void*)xg0[0], G_);

  const dim3 grid(32 + 4*TC);
  for (int i = 0; i <= nc + 1; ++i){
    int mask = 0;
    if (i < nc)            mask |= 1;   // L0 scans chunk i
    if (i >= 2)            mask |= 2;   // L1 scans chunk i-2
    if (i + 1 < nc)        mask |= 4;   // gemm0 builds chunk i+1
    if (i >= 1 && i <= nc) mask |= 8;   // gemm1 builds chunk i-1
    hipLaunchKernelGGL(fused, grid, dim3(512), 0, stream,
                       xg0[i&1], Whh0h, bhh0, h0s, out0[i&1],
                       xg1[i&1], Whh1h, bhh1, h1s,
                       xb + (size_t)(i+1)*TC*B_*KX, W0h, bias0, xg0[(i+1)&1],
                       out0[(i+1)&1], Wih1h, bias1, xg1[(i+1)&1],
                       TC, mask);
  }

  // embedding = hT @ fc_W^T + fc_b (f32 out)
  hipLaunchKernelGGL(cast_h, dim3(256), dim3(256), 0, stream, h1s, hTh);
  hipLaunchKernelGGL((gemm_k<256,64,true>), dim3(2,4), dim3(256), 0, stream,
                     hTh, fcWh, fcb, d_out, H_);
}

// Round 4
// 1917.068 us; speedup vs baseline: 2.4386x; 1.0202x over previous
//
#include <hip/hip_runtime.h>
#include <hip/hip_bf16.h>
#include <stdint.h>
#include <stddef.h>

// ---------------------------------------------------------------------------
// GRUEncoder: x[256,512,25,3] f32 -> 2-layer GRU(H=256) -> fc(hT) -> [256,256] f32
//
// Fused pipelined schedule (chunk = TC steps, 2-chunk layer skew):
//   cast_x ; cast_w ; gemm0(chunk0)
//   for i in 0..nc+1:   ONE launch: [scan L0 chunk i] || [scan L1 chunk i-2]
//                                   || [gemm0 chunk i+1] || [gemm1 chunk i-1]
//   cast_h ; fc gemm
//
// Scan, swapped MFMA operands: D[gate rows x batch cols] = Whh * h.
// LESSON (r1-r3): the arch-VGPR allocator collapses to 128 regs for this
// kernel no matter what launch bounds ask; pinned VGPR weights then spill to
// scratch and the per-step scratch reload (~320KB/WG) dominates. So this
// build is correct AT an arch allocation of 128:
//   - r,z weights pinned in AGPRs ("a" asm constraint; MFMA reads A-operand
//     from AGPR on gfx950; separate descriptor region from arch VGPRs)
//     -> 32 frags = 128 AGPR
//   - n-gate weights streamed from LDS (128KB, exact A-frag order,
//     coalesced ds_read_b128)
//   - arch working set ~100 regs < 128  => no spill by construction
//   - hbuf XOR-swizzled (chunk ^= row&7): conflict-free b128 reads
// ---------------------------------------------------------------------------

typedef _Float16 f16;
typedef _Float16 f16x8 __attribute__((ext_vector_type(8)));
typedef _Float16 f16x4 __attribute__((ext_vector_type(4)));
typedef float    f32x4 __attribute__((ext_vector_type(4)));

#define B_      256
#define T_      512
#define H_      256
#define G_      768      // 3*H
#define IN_RAW  75
#define KX      96       // padded input K
#define MROWS   (T_*B_)  // 131072

__device__ __forceinline__ float sigm(float x){ return 1.f/(1.f+__expf(-x)); }
__device__ __forceinline__ float tanh_(float x){ return 1.f - 2.f/(1.f+__expf(2.f*x)); }

// --------------------------------------------------------------------------
// cast_x: x[b][t][j] (f32) -> xb[t*256+b][96] (fp16, j>=75 zero)
// --------------------------------------------------------------------------
__global__ __launch_bounds__(256) void cast_x(const float* __restrict__ x,
                                              f16* __restrict__ xb){
  int idx = blockIdx.x*256 + threadIdx.x;        // grid*256 == 131072*96 exact
  int row = idx / KX;
  int j   = idx - row*KX;
  int t   = row >> 8;        // row = t*256 + b
  int b   = row & 255;
  float v = (j < IN_RAW) ? x[((size_t)b*T_ + t)*IN_RAW + j] : 0.f;
  xb[idx] = (f16)v;
}

// --------------------------------------------------------------------------
// cast_w: all weight casts + fused biases. grid*256 == 730624 exact.
// --------------------------------------------------------------------------
__global__ __launch_bounds__(256) void cast_w(
    const float* __restrict__ Wih0, const float* __restrict__ Whh0,
    const float* __restrict__ Wih1, const float* __restrict__ Whh1,
    const float* __restrict__ fcW,
    const float* __restrict__ bih0, const float* __restrict__ bhh0,
    const float* __restrict__ bih1, const float* __restrict__ bhh1,
    f16* __restrict__ W0h, f16* __restrict__ Whh0h, f16* __restrict__ Wih1h,
    f16* __restrict__ Whh1h, f16* __restrict__ fcWh,
    float* __restrict__ bias0, float* __restrict__ bias1){
  int i = blockIdx.x*256 + threadIdx.x;
  if (i < 73728){ int r = i/KX, j = i - r*KX;
    W0h[i] = (f16)((j < IN_RAW) ? Wih0[r*IN_RAW + j] : 0.f); return; }
  i -= 73728;
  if (i < 196608){ Whh0h[i] = (f16)Whh0[i]; return; } i -= 196608;
  if (i < 196608){ Wih1h[i] = (f16)Wih1[i]; return; } i -= 196608;
  if (i < 196608){ Whh1h[i] = (f16)Whh1[i]; return; } i -= 196608;
  if (i < 65536){ fcWh[i] = (f16)fcW[i]; return; } i -= 65536;
  if (i < 768){ bias0[i] = bih0[i] + (i < 512 ? bhh0[i] : 0.f); return; } i -= 768;
  if (i < 768){ bias1[i] = bih1[i] + (i < 512 ? bhh1[i] : 0.f); }
}

// --------------------------------------------------------------------------
// cast_h: h1s f32 [256*256] -> hT fp16
// --------------------------------------------------------------------------
__global__ __launch_bounds__(256) void cast_h(const float* __restrict__ hs,
                                              f16* __restrict__ hT){
  int i = blockIdx.x*256 + threadIdx.x;
  hT[i] = (f16)hs[i];
}

// --------------------------------------------------------------------------
// gemm_k: out[M,N] = A[M,K](fp16) @ W[N,K]^T(fp16) + bias. 256-thread version
// for the prologue gemm and the fc epilogue.
// --------------------------------------------------------------------------
template<int K, int BN, bool OUTF32>
__global__ __launch_bounds__(256, 2) void gemm_k(const f16* __restrict__ A,
    const f16* __restrict__ W, const float* __restrict__ bias,
    void* __restrict__ outp, const int N){
  constexpr int NT = BN/16;
  const int tid  = threadIdx.x;
  const int wave = tid >> 6, lane = tid & 63;
  const int quad = lane >> 4, l16 = lane & 15;
  const long mbase = (long)blockIdx.x*128 + wave*32;
  const int  nbase = blockIdx.y*BN;
  f32x4 acc[2][NT] = {};
#pragma unroll 2
  for (int kc = 0; kc < K/32; ++kc){
    f16x8 a0 = *(const f16x8*)(A + (mbase +      l16)*K + kc*32 + quad*8);
    f16x8 a1 = *(const f16x8*)(A + (mbase + 16 + l16)*K + kc*32 + quad*8);
#pragma unroll
    for (int nt = 0; nt < NT; ++nt){
      f16x8 b = *(const f16x8*)(W + (long)(nbase + nt*16 + l16)*K + kc*32 + quad*8);
      acc[0][nt] = __builtin_amdgcn_mfma_f32_16x16x32_f16(a0, b, acc[0][nt], 0, 0, 0);
      acc[1][nt] = __builtin_amdgcn_mfma_f32_16x16x32_f16(a1, b, acc[1][nt], 0, 0, 0);
    }
  }
#pragma unroll
  for (int nt = 0; nt < NT; ++nt){
    const int col = nbase + nt*16 + l16;
    const float bv = bias[col];
#pragma unroll
    for (int af = 0; af < 2; ++af){
#pragma unroll
      for (int r = 0; r < 4; ++r){
        const long row = mbase + af*16 + quad*4 + r;   // D row = quad*4 + reg
        float v = acc[af][nt][r] + bv;
        if (OUTF32) ((float*)outp)[row*(long)N + col] = v;
        else        ((f16*)outp)[row*(long)N + col] = (f16)v;
      }
    }
  }
}

// --------------------------------------------------------------------------
// gemm_body128: 512-thread (8-wave) GEMM tile for the fused kernel.
// Block covers 512 rows (2 sequential 256-row tiles) x 128 cols, N=768.
// acc = 2x8 f32x4 = 64 regs -> gemm path stays well under 128 arch VGPRs.
// --------------------------------------------------------------------------
template<int K>
__device__ __forceinline__ void gemm_body128(const f16* __restrict__ A,
    const f16* __restrict__ W, const float* __restrict__ bias,
    f16* __restrict__ out, const int bx, const int by){
  const int tid  = threadIdx.x;
  const int wave = tid >> 6, lane = tid & 63;
  const int quad = lane >> 4, l16 = lane & 15;
  const int nbase = by*128;
#pragma unroll
  for (int mt = 0; mt < 2; ++mt){
    const long mbase = (long)bx*512 + mt*256 + wave*32;
    f32x4 acc[2][8] = {};
#pragma unroll 2
    for (int kc = 0; kc < K/32; ++kc){
      f16x8 a0 = *(const f16x8*)(A + (mbase +      l16)*K + kc*32 + quad*8);
      f16x8 a1 = *(const f16x8*)(A + (mbase + 16 + l16)*K + kc*32 + quad*8);
#pragma unroll
      for (int nt = 0; nt < 8; ++nt){
        f16x8 b = *(const f16x8*)(W + (long)(nbase + nt*16 + l16)*K + kc*32 + quad*8);
        acc[0][nt] = __builtin_amdgcn_mfma_f32_16x16x32_f16(a0, b, acc[0][nt], 0, 0, 0);
        acc[1][nt] = __builtin_amdgcn_mfma_f32_16x16x32_f16(a1, b, acc[1][nt], 0, 0, 0);
      }
    }
#pragma unroll
    for (int nt = 0; nt < 8; ++nt){
      const int col = nbase + nt*16 + l16;
      const float bv = bias[col];
#pragma unroll
      for (int af = 0; af < 2; ++af)
#pragma unroll
        for (int r = 0; r < 4; ++r)
          out[(mbase + af*16 + quad*4 + r)*(long)G_ + col] = (f16)(acc[af][nt][r] + bv);
    }
  }
}

// --------------------------------------------------------------------------
// scan_body: TC steps of one GRU layer, swapped-operand, AGPR-resident r,z.
// 16 WGs x 512 thr (8 waves); WG owns batch rows [bx*16,+16).
// D[gate rows x batch cols] = Whh(A) * h(B, from swizzled hbuf).
// Wave owns gate rows [w*32,+32) of r/z/n.
//   r,z (all kc): 32 frags = 128 AGPR, pinned via "a" asm constraint
//   n (all kc):   streamed from nlds (128KB, A-frag order, coalesced b128)
// hbuf: byte layout row*512 + ((chunk ^ (row&7))<<4)  -> conflict-free reads.
// Gate inputs xg loaded global->cur after last use; 1 barrier/step.
// --------------------------------------------------------------------------
__device__ __forceinline__ void scan_body(const f16* __restrict__ xg,
    const f16* __restrict__ Whh, const float* __restrict__ bhh,
    float* __restrict__ hstate, f16* __restrict__ out0,
    const int TC, const int bx){
  __shared__ char  hbufB[2][16*512];   // 16 KB: h(t) fp16, XOR-swizzled
  __shared__ f16   nlds[65536];        // 128 KB: full n-gate, A-frag order
  __shared__ float bnlds[256];         // n-gate hidden bias
  const int tid  = threadIdx.x;
  const int wave = tid >> 6, lane = tid & 63;
  const int quad = lane >> 4, l16 = lane & 15;
  const int b0   = bx*16;
  const int jj   = wave*32 + quad*4;   // D-row (hidden) base; s adds 16

  // r,z A-frags: Whh[gate_row][k]; 8 consecutive k per lane -> AGPR-pinned
  f16x8 w[2][2][8];   // [s][g: r,z][kc]
#pragma unroll
  for (int s = 0; s < 2; ++s)
#pragma unroll
    for (int g = 0; g < 2; ++g)
#pragma unroll
      for (int kc = 0; kc < 8; ++kc)
        w[s][g][kc] = *(const f16x8*)(Whh + (size_t)(g*256 + wave*32 + s*16 + l16)*H_ + kc*32 + quad*8);
#pragma unroll
  for (int s = 0; s < 2; ++s)
#pragma unroll
    for (int g = 0; g < 2; ++g)
#pragma unroll
      for (int kc = 0; kc < 8; ++kc)
        asm volatile("" : "+a"(w[s][g][kc]));   // pin in AGPRs (separate file)

  // stage nlds: piece p = f*64+L, f = wave<<4 | s<<3 | kc; 16B per piece
#pragma unroll
  for (int i = 0; i < 16; ++i){
    const int p  = i*512 + tid;            // 8192 pieces total
    const int f  = p >> 6, L = p & 63;
    const int wv = f >> 4, ss = (f >> 3) & 1, kcc = f & 7;
    const int row = 512 + wv*32 + ss*16 + (L & 15);
    const int k   = kcc*32 + (L >> 4)*8;
    *(f16x8*)&nlds[(size_t)p*8] = *(const f16x8*)(Whh + (size_t)row*H_ + k);
  }
  if (tid < 256) bnlds[tid] = bhh[512 + tid];

  // h state: lane owns (batch=l16, hidden j=jj+s*16+r)
  f32x4 h[2];
#pragma unroll
  for (int s = 0; s < 2; ++s){
    h[s] = *(const f32x4*)(hstate + (size_t)(b0 + l16)*H_ + jj + s*16);
    f16x4 hh;
#pragma unroll
    for (int r = 0; r < 4; ++r) hh[r] = (f16)h[s][r];
    const int ch = wave*4 + s*2 + (quad>>1);                // 16B chunk index
    *(f16x4*)&hbufB[0][l16*512 + ((ch ^ (l16&7))<<4) + ((quad&1)<<3)] = hh;
  }

  // per-lane xg base: row = b0+l16, cols jj + {g*256, s*16}
  const f16* xgl = xg + (size_t)(b0 + l16)*G_ + jj;
  f16x4 cur[6];
#pragma unroll
  for (int s = 0; s < 2; ++s)
#pragma unroll
    for (int g = 0; g < 3; ++g)
      cur[s*3+g] = *(const f16x4*)(xgl + g*256 + s*16);

  __syncthreads();   // hbuf[0], nlds, bnlds ready

  for (int t = 0; t < TC; ++t){
    const int pb = t & 1;
    f32x4 acc[2][3] = {};
#pragma unroll
    for (int kc = 0; kc < 8; ++kc){
      // B-frag: h[batch=l16][k=kc*32+quad*8], swizzled chunk = kc*4+quad
      f16x8 hf = *(const f16x8*)&hbufB[pb][l16*512 + ((((kc<<2)|quad) ^ (l16&7))<<4)];
#pragma unroll
      for (int s = 0; s < 2; ++s){
        acc[s][0] = __builtin_amdgcn_mfma_f32_16x16x32_f16(w[s][0][kc], hf, acc[s][0], 0,0,0);
        acc[s][1] = __builtin_amdgcn_mfma_f32_16x16x32_f16(w[s][1][kc], hf, acc[s][1], 0,0,0);
        f16x8 nf = *(const f16x8*)&nlds[(size_t)(((wave<<4)|(s<<3)|kc)*64 + lane)*8];
        acc[s][2] = __builtin_amdgcn_mfma_f32_16x16x32_f16(nf, hf, acc[s][2], 0,0,0);
      }
    }
    f16x4 hh[2];
#pragma unroll
    for (int s = 0; s < 2; ++s){
      const f32x4 bnv = *(const f32x4*)&bnlds[jj + s*16];
#pragma unroll
      for (int r = 0; r < 4; ++r){
        float rg = sigm((float)cur[s*3+0][r] + acc[s][0][r]);
        float zg = sigm((float)cur[s*3+1][r] + acc[s][1][r]);
        float ng = tanh_((float)cur[s*3+2][r] + rg*(acc[s][2][r] + bnv[r]));
        float hv = (1.f - zg)*ng + zg*h[s][r];
        h[s][r] = hv;
        hh[s][r] = (f16)hv;
      }
    }
    if (t+1 < TC){  // load t+1 gates into cur (old cur fully consumed above);
      const f16* xn_ = xgl + (size_t)(t+1)*(B_*G_);   // latency covered by
#pragma unroll                                        // barrier + next MFMA
      for (int s = 0; s < 2; ++s)
#pragma unroll
        for (int g = 0; g < 3; ++g)
          cur[s*3+g] = *(const f16x4*)(xn_ + g*256 + s*16);
    }
#pragma unroll
    for (int s = 0; s < 2; ++s){
      const int ch = wave*4 + s*2 + (quad>>1);
      *(f16x4*)&hbufB[pb^1][l16*512 + ((ch ^ (l16&7))<<4) + ((quad&1)<<3)] = hh[s];
      if (out0)
        *(f16x4*)(out0 + ((size_t)t*B_ + b0 + l16)*H_ + jj + s*16) = hh[s];
    }
    __syncthreads();   // h(t) visible in hbuf[pb^1] for step t+1
  }

#pragma unroll
  for (int s = 0; s < 2; ++s)
    *(f32x4*)(hstate + (size_t)(b0 + l16)*H_ + jj + s*16) = h[s];
}

// --------------------------------------------------------------------------
// fused: [scan L0] || [scan L1] || [gemm0 next chunk] || [gemm1 prev chunk]
// blocks: [0,16) L0, [16,32) L1, [32,32+3TC) gemm0, [32+3TC,32+6TC) gemm1.
// mask: bit0 L0, bit1 L1, bit2 gemm0, bit3 gemm1.  grid = 32+6TC (<=224).
// --------------------------------------------------------------------------
__global__ __launch_bounds__(512)
__attribute__((amdgpu_waves_per_eu(2, 2)))
void fused(
    const f16* __restrict__ xg0, const f16* __restrict__ Whh0,
    const float* __restrict__ bhh0, float* __restrict__ h0s,
    f16* __restrict__ out0w,
    const f16* __restrict__ xg1, const f16* __restrict__ Whh1,
    const float* __restrict__ bhh1, float* __restrict__ h1s,
    const f16* __restrict__ g0A, const f16* __restrict__ g0W,
    const float* __restrict__ g0b, f16* __restrict__ g0out,
    const f16* __restrict__ g1A, const f16* __restrict__ g1W,
    const float* __restrict__ g1b, f16* __restrict__ g1out,
    const int TC, const int mask){
  const int bid = blockIdx.x;
  if (bid < 16){
    if (!(mask & 1)) return;
    scan_body(xg0, Whh0, bhh0, h0s, out0w, TC, bid);
  } else if (bid < 32){
    if (!(mask & 2)) return;
    scan_body(xg1, Whh1, bhh1, h1s, (f16*)nullptr, TC, bid - 16);
  } else {
    int g = bid - 32;
    const int RB = TC/2;                 // 512-row blocks per gemm
    if (g < 3*TC){
      if (!(mask & 4)) return;
      gemm_body128<96>(g0A, g0W, g0b, g0out, g % RB, g / RB);
    } else {
      g -= 3*TC;
      if (!(mask & 8)) return;
      gemm_body128<256>(g1A, g1W, g1b, g1out, g % RB, g / RB);
    }
  }
}

// --------------------------------------------------------------------------
extern "C" void kernel_launch(void* const* d_in, const int* in_sizes, int n_in,
                              void* d_out, int out_size, void* d_ws, size_t ws_size,
                              hipStream_t stream){
  (void)in_sizes; (void)n_in; (void)out_size;
  const float* x    = (const float*)d_in[0];
  const float* Wih0 = (const float*)d_in[1];
  const float* Whh0 = (const float*)d_in[2];
  const float* bih0 = (const float*)d_in[3];
  const float* bhh0 = (const float*)d_in[4];
  const float* Wih1 = (const float*)d_in[5];
  const float* Whh1 = (const float*)d_in[6];
  const float* bih1 = (const float*)d_in[7];
  const float* bhh1 = (const float*)d_in[8];
  const float* fcW  = (const float*)d_in[9];
  const float* fcb  = (const float*)d_in[10];

  char* ws = (char*)d_ws;
  size_t off = 0;
  auto alloc = [&](size_t bytes) -> void* {
    void* p = ws + off; off += (bytes + 255) & ~(size_t)255; return p;
  };
  f16*   xb    = (f16*)  alloc((size_t)MROWS*KX*2);   // 25.2 MB
  f16*   W0h   = (f16*)  alloc((size_t)G_*KX*2);
  f16*   Whh0h = (f16*)  alloc((size_t)G_*H_*2);
  f16*   Wih1h = (f16*)  alloc((size_t)G_*H_*2);
  f16*   Whh1h = (f16*)  alloc((size_t)G_*H_*2);
  f16*   fcWh  = (f16*)  alloc((size_t)H_*H_*2);
  float* bias0 = (float*)alloc(G_*4);
  float* bias1 = (float*)alloc(G_*4);
  float* h0s   = (float*)alloc((size_t)B_*H_*4);      // h-state, both layers
  float* h1s   = (float*)alloc((size_t)B_*H_*4);      //   (adjacent: one memset)
  f16*   hTh   = (f16*)  alloc((size_t)B_*H_*2);
  const size_t fixed = off;

  // TC=32: double-buffered xg (both layers) + out0. Per-TC bytes:
  // 4*B*G*2 + 2*B*H*2 = 1,835,008. Fallback shrink if ws is tight.
  int TC = 32;
  while (TC > 8 && fixed + (size_t)TC*1835008 + 1024 > ws_size) TC >>= 1;
  f16* xg0[2], *xg1[2], *out0[2];
  xg0[0]  = (f16*)alloc((size_t)TC*B_*G_*2);
  xg0[1]  = (f16*)alloc((size_t)TC*B_*G_*2);
  xg1[0]  = (f16*)alloc((size_t)TC*B_*G_*2);
  xg1[1]  = (f16*)alloc((size_t)TC*B_*G_*2);
  out0[0] = (f16*)alloc((size_t)TC*B_*H_*2);
  out0[1] = (f16*)alloc((size_t)TC*B_*H_*2);
  const int nc = T_ / TC;

  hipMemsetAsync(h0s, 0, (size_t)B_*H_*4*2, stream);  // zero h0s+h1s (adjacent)
  hipLaunchKernelGGL(cast_x, dim3(49152), dim3(256), 0, stream, x, xb);
  hipLaunchKernelGGL(cast_w, dim3(2854), dim3(256), 0, stream,
                     Wih0, Whh0, Wih1, Whh1, fcW, bih0, bhh0, bih1, bhh1,
                     W0h, Whh0h, Wih1h, Whh1h, fcWh, bias0, bias1);

  // prologue: xg0[0] = xb[chunk 0] @ W_ih0^T + bias0
  hipLaunchKernelGGL((gemm_k<96,192,false>), dim3(TC*2,4), dim3(256), 0, stream,
                     xb, W0h, bias0, (void*)xg0[0], G_);

  const dim3 grid(32 + 6*TC);
  for (int i = 0; i <= nc + 1; ++i){
    int mask = 0;
    if (i < nc)            mask |= 1;   // L0 scans chunk i
    if (i >= 2)            mask |= 2;   // L1 scans chunk i-2
    if (i + 1 < nc)        mask |= 4;   // gemm0 builds chunk i+1
    if (i >= 1 && i <= nc) mask |= 8;   // gemm1 builds chunk i-1
    hipLaunchKernelGGL(fused, grid, dim3(512), 0, stream,
                       xg0[i&1], Whh0h, bhh0, h0s, out0[i&1],
                       xg1[i&1], Whh1h, bhh1, h1s,
                       xb + (size_t)(i+1)*TC*B_*KX, W0h, bias0, xg0[(i+1)&1],
                       out0[(i+1)&1], Wih1h, bias1, xg1[(i+1)&1],
                       TC, mask);
  }

  // embedding = hT @ fc_W^T + fc_b (f32 out)
  hipLaunchKernelGGL(cast_h, dim3(256), dim3(256), 0, stream, h1s, hTh);
  hipLaunchKernelGGL((gemm_k<256,64,true>), dim3(2,4), dim3(256), 0, stream,
                     hTh, fcWh, fcb, d_out, H_);
}